// Round 5
// baseline (316.902 us; speedup 1.0000x reference)
//
#include <hip/hip_runtime.h>
#include <math.h>

#define NUM 2048
#define CDIM 256
#define NUM_LAYER 4

// ---------------- projection: out[b][n][oc] = sum_c W[oc][c] x[b][c][n] + bias[oc]
__global__ __launch_bounds__(256) void proj_kernel(
    const float* __restrict__ Wq, const float* __restrict__ bq,
    const float* __restrict__ Wk, const float* __restrict__ bk,
    const float* __restrict__ vf, const float* __restrict__ ef,
    float* __restrict__ QT, float* __restrict__ KT)
{
  const int z = blockIdx.z;
  const int b = z >> 1, m = z & 1;
  const float* __restrict__ Wmat = m ? Wk : Wq;
  const float* __restrict__ bias = m ? bk : bq;
  const float* __restrict__ x = (m ? ef : vf) + (size_t)b * CDIM * NUM;
  float* __restrict__ out = (m ? KT : QT) + (size_t)b * NUM * CDIM;

  const int n0 = blockIdx.x * 64;
  const int o0 = blockIdx.y * 64;
  __shared__ float Xs[32][65];
  __shared__ float Ws[64][33];
  const int t = threadIdx.x;
  const int tx = t & 15, ty = t >> 4;

  float acc[4][4];
  #pragma unroll
  for (int a = 0; a < 4; a++)
    #pragma unroll
    for (int c = 0; c < 4; c++) acc[a][c] = 0.0f;

  for (int cc = 0; cc < CDIM; cc += 32) {
    #pragma unroll
    for (int e = 0; e < 2; e++) {
      int f = t * 2 + e;
      int row = f >> 4, c4 = f & 15;
      const float4 v = *(const float4*)(&x[(size_t)(cc + row) * NUM + n0 + c4 * 4]);
      Xs[row][c4*4+0] = v.x; Xs[row][c4*4+1] = v.y;
      Xs[row][c4*4+2] = v.z; Xs[row][c4*4+3] = v.w;
    }
    #pragma unroll
    for (int e = 0; e < 2; e++) {
      int f = t * 2 + e;
      int row = f >> 3, c4 = f & 7;
      const float4 v = *(const float4*)(&Wmat[(size_t)(o0 + row) * CDIM + cc + c4 * 4]);
      Ws[row][c4*4+0] = v.x; Ws[row][c4*4+1] = v.y;
      Ws[row][c4*4+2] = v.z; Ws[row][c4*4+3] = v.w;
    }
    __syncthreads();
    #pragma unroll
    for (int kk = 0; kk < 32; kk++) {
      float xv[4], wv[4];
      #pragma unroll
      for (int j = 0; j < 4; j++) xv[j] = Xs[kk][tx*4+j];
      #pragma unroll
      for (int j = 0; j < 4; j++) wv[j] = Ws[ty*4+j][kk];
      #pragma unroll
      for (int oi = 0; oi < 4; oi++)
        #pragma unroll
        for (int ni = 0; ni < 4; ni++)
          acc[oi][ni] = fmaf(wv[oi], xv[ni], acc[oi][ni]);
    }
    __syncthreads();
  }
  float bb[4];
  #pragma unroll
  for (int oi = 0; oi < 4; oi++) bb[oi] = bias[o0 + ty*4 + oi];
  #pragma unroll
  for (int ni = 0; ni < 4; ni++) {
    float4 v;
    v.x = acc[0][ni] + bb[0];
    v.y = acc[1][ni] + bb[1];
    v.z = acc[2][ni] + bb[2];
    v.w = acc[3][ni] + bb[3];
    *(float4*)(&out[(size_t)(n0 + tx*4 + ni) * CDIM + o0 + ty*4]) = v;
  }
}

// ---------------- score[b][o][i] = H0 * (1/8) * sum_h sigmoid(dot_h / sqrt(32))
// 128x128 tile, 256 threads, 8(o) x 8(i) per thread. LDS layout [k][n] with
// XOR swizzle on the COLUMN OFFSET (col ^ (k&28)), applied before adding the
// k*132 row base. SC MUST be the folded product (round-3 literal was a
// mis-transcription that flipped top-k selections).
__global__ __launch_bounds__(256, 3) void score_kernel(
    const float* __restrict__ QT, const float* __restrict__ KT,
    const float* __restrict__ H0, float* __restrict__ score)
{
  const int b = blockIdx.z;
  const int i0 = blockIdx.x * 128;
  const int o0 = blockIdx.y * 128;
  const float* __restrict__ Qb = QT + (size_t)b * NUM * CDIM;
  const float* __restrict__ Kb = KT + (size_t)b * NUM * CDIM;
  __shared__ float qs[32 * 132];
  __shared__ float ks[32 * 132];
  const int t = threadIdx.x;
  const int lane = t & 63, wave = t >> 6;
  const int ifr = lane & 7, ofr = lane >> 3;
  const int i_off = (wave & 1) * 64 + ifr * 8;
  const int o_off = (wave >> 1) * 64 + ofr * 8;

  float ssum[8][8];
  #pragma unroll
  for (int a = 0; a < 8; a++)
    #pragma unroll
    for (int c = 0; c < 8; c++) ssum[a][c] = 0.0f;

  const float SC = -1.4426950408889634f * 0.17677669529663687f;  // -log2(e)/sqrt(32) = -0.25503486
  const int row_s = t >> 3, c4 = t & 7;
  const int swz_st = c4 << 2;              // == k&28 for k = c4*4+qq, qq<4

  for (int h = 0; h < 8; h++) {
    #pragma unroll
    for (int e = 0; e < 4; e++) {
      const int row = row_s + 32 * e;
      const int rc = row ^ swz_st;
      const float4 q = *(const float4*)(&Qb[(size_t)(o0 + row) * CDIM + h*32 + c4*4]);
      qs[(c4*4+0)*132 + rc] = q.x; qs[(c4*4+1)*132 + rc] = q.y;
      qs[(c4*4+2)*132 + rc] = q.z; qs[(c4*4+3)*132 + rc] = q.w;
      const float4 kv = *(const float4*)(&Kb[(size_t)(i0 + row) * CDIM + h*32 + c4*4]);
      ks[(c4*4+0)*132 + rc] = kv.x; ks[(c4*4+1)*132 + rc] = kv.y;
      ks[(c4*4+2)*132 + rc] = kv.z; ks[(c4*4+3)*132 + rc] = kv.w;
    }
    __syncthreads();
    float acc[8][8];
    #pragma unroll
    for (int a = 0; a < 8; a++)
      #pragma unroll
      for (int c = 0; c < 8; c++) acc[a][c] = 0.0f;
    #pragma unroll 4
    for (int kk = 0; kk < 32; kk++) {
      const int g = kk & 28;
      const int rowbase = kk * 132;
      const int oq = o_off ^ g;          // column offset of o_off..o_off+3
      const int iq = i_off ^ g;
      const float4 qa  = *(const float4*)(&qs[rowbase + oq]);
      const float4 qbv = *(const float4*)(&qs[rowbase + (oq ^ 4)]);  // o_off+4..7
      const float4 ka  = *(const float4*)(&ks[rowbase + iq]);
      const float4 kbv = *(const float4*)(&ks[rowbase + (iq ^ 4)]);
      const float qv[8] = {qa.x, qa.y, qa.z, qa.w, qbv.x, qbv.y, qbv.z, qbv.w};
      const float kv[8] = {ka.x, ka.y, ka.z, ka.w, kbv.x, kbv.y, kbv.z, kbv.w};
      #pragma unroll
      for (int oj = 0; oj < 8; oj++)
        #pragma unroll
        for (int ij = 0; ij < 8; ij++)
          acc[oj][ij] = fmaf(qv[oj], kv[ij], acc[oj][ij]);
    }
    __syncthreads();
    #pragma unroll
    for (int oj = 0; oj < 8; oj++)
      #pragma unroll
      for (int ij = 0; ij < 8; ij++) {
        float z = __builtin_amdgcn_exp2f(acc[oj][ij] * SC);
        ssum[oj][ij] += __builtin_amdgcn_rcpf(1.0f + z);
      }
  }
  #pragma unroll
  for (int oj = 0; oj < 8; oj++) {
    const int o = o0 + o_off + oj;
    const size_t base = ((size_t)b * NUM + o) * NUM + i0 + i_off;
    const float4 h0a = *(const float4*)(&H0[base]);
    const float4 h0b = *(const float4*)(&H0[base + 4]);
    float4 sa, sb;
    sa.x = h0a.x * ssum[oj][0] * 0.125f;
    sa.y = h0a.y * ssum[oj][1] * 0.125f;
    sa.z = h0a.z * ssum[oj][2] * 0.125f;
    sa.w = h0a.w * ssum[oj][3] * 0.125f;
    sb.x = h0b.x * ssum[oj][4] * 0.125f;
    sb.y = h0b.y * ssum[oj][5] * 0.125f;
    sb.z = h0b.z * ssum[oj][6] * 0.125f;
    sb.w = h0b.w * ssum[oj][7] * 0.125f;
    *(float4*)(&score[base]) = sa;
    *(float4*)(&score[base + 4]) = sb;
  }
}

// ---------------- fused: exact k-th largest (radix select on float bits, all >= 0)
// + W/H write + row count -> Dv + column sums (atomics; only ~k nonzero/row).
__global__ __launch_bounds__(256) void topk_apply_kernel(
    float* __restrict__ scoreW, float* __restrict__ Hout,
    const int* __restrict__ iterp, float* __restrict__ DvOut,
    float* __restrict__ colH, float* __restrict__ colW)
{
  const int row = blockIdx.x;
  const int b = row >> 11;
  __shared__ unsigned int hist[4][256];
  __shared__ unsigned int cum[257];
  __shared__ unsigned int s_sel, s_rem;
  __shared__ float red[4];
  const int t = threadIdx.x;
  const int wid = t >> 6, lane = t & 63;
  unsigned int* __restrict__ srow = (unsigned int*)scoreW + (size_t)row * NUM;

  unsigned int v[8];
  #pragma unroll
  for (int j = 0; j < 8; j++) v[j] = srow[t + 256*j];

  const int it = iterp[0];
  int k = (int)((double)NUM * 0.1 * (double)(NUM_LAYER - 1 - it) + 0.5);
  if (k < 1) k = 1;
  if (k > NUM) k = NUM;

  unsigned int prefix = 0;
  unsigned int rem = (unsigned int)k;
  unsigned int* hflat = &hist[0][0];

  for (int pass = 3; pass >= 0; pass--) {
    const int shift = pass * 8;
    const unsigned int pmask = (pass == 3) ? 0u : (0xFFFFFFFFu << (shift + 8));
    #pragma unroll
    for (int j = 0; j < 4; j++) hflat[t + 256*j] = 0;
    __syncthreads();
    unsigned int zc = 0;
    #pragma unroll
    for (int j = 0; j < 8; j++) {
      unsigned int val = v[j];
      if ((val & pmask) == prefix) {
        unsigned int bin = (val >> shift) & 255u;
        if (bin) atomicAdd(&hist[wid][bin], 1u);
        else zc++;
      }
    }
    #pragma unroll
    for (int off = 32; off > 0; off >>= 1) zc += __shfl_down(zc, off, 64);
    if (lane == 0 && zc) atomicAdd(&hist[wid][0], zc);
    __syncthreads();
    if (t < 64) {
      unsigned int T[4], s[4];
      #pragma unroll
      for (int q = 0; q < 4; q++)
        T[q] = hist[0][t*4+q] + hist[1][t*4+q] + hist[2][t*4+q] + hist[3][t*4+q];
      s[3] = T[3];
      s[2] = T[2] + s[3];
      s[1] = T[1] + s[2];
      s[0] = T[0] + s[1];
      unsigned int tot = s[0];
      #pragma unroll
      for (int off = 1; off < 64; off <<= 1) {
        unsigned int y = __shfl_down(tot, off, 64);
        if (lane + off < 64) tot += y;
      }
      const unsigned int above_chunk = tot - s[0];
      #pragma unroll
      for (int q = 0; q < 4; q++) cum[t*4+q] = s[q] + above_chunk;
      if (t == 0) cum[256] = 0;
    }
    __syncthreads();
    unsigned int c = cum[t], above = cum[t + 1];
    if (c >= rem && above < rem) { s_sel = (unsigned int)t; s_rem = rem - above; }
    __syncthreads();
    prefix |= (s_sel << shift);
    rem = s_rem;
    __syncthreads();
  }

  const unsigned int amin = prefix;
  float* __restrict__ Hrow = Hout + (size_t)row * NUM;
  float cnt = 0.0f;
  #pragma unroll
  for (int j = 0; j < 8; j++) {
    const int i = t + 256*j;
    unsigned int val = v[j];
    unsigned int w = (val >= amin) ? val : 0u;
    float hh = (w != 0u) ? 1.0f : 0.0f;
    srow[i] = w;
    Hrow[i] = hh;
    cnt += hh;
    if (w != 0u) {
      atomicAdd(&colW[b * NUM + i], __uint_as_float(w));
      atomicAdd(&colH[b * NUM + i], 1.0f);
    }
  }
  #pragma unroll
  for (int off = 32; off > 0; off >>= 1) cnt += __shfl_down(cnt, off, 64);
  if (lane == 0) red[wid] = cnt;
  __syncthreads();
  if (t == 0) {
    float tot = red[0] + red[1] + red[2] + red[3];
    DvOut[row] = 1.0f / (tot + 1e-10f);
  }
}

// ---------------- De = 1/(colH+eps); W_edge = colW / max(||colW||_2, 1e-12)
__global__ __launch_bounds__(1024) void finalize_kernel(
    const float* __restrict__ colH, const float* __restrict__ colW,
    float* __restrict__ De, float* __restrict__ We)
{
  const int b = blockIdx.x;
  const int t = threadIdx.x;
  float cw[2];
  float sq = 0.0f;
  #pragma unroll
  for (int j = 0; j < 2; j++) {
    int i = t + 1024*j;
    float ch = colH[b * NUM + i];
    De[b * NUM + i] = 1.0f / (ch + 1e-10f);
    cw[j] = colW[b * NUM + i];
    sq += cw[j] * cw[j];
  }
  for (int off = 32; off > 0; off >>= 1) sq += __shfl_down(sq, off, 64);
  __shared__ float red[16];
  __shared__ float s_nrm;
  if ((t & 63) == 0) red[t >> 6] = sq;
  __syncthreads();
  if (t == 0) {
    float tot = 0.0f;
    for (int i2 = 0; i2 < 16; i2++) tot += red[i2];
    s_nrm = fmaxf(sqrtf(tot), 1e-12f);
  }
  __syncthreads();
  #pragma unroll
  for (int j = 0; j < 2; j++)
    We[b * NUM + t + 1024*j] = cw[j] / s_nrm;
}

extern "C" void kernel_launch(void* const* d_in, const int* in_sizes, int n_in,
                              void* d_out, int out_size, void* d_ws, size_t ws_size,
                              hipStream_t stream) {
  const float* H0 = (const float*)d_in[0];
  const float* vf = (const float*)d_in[1];
  const float* ef = (const float*)d_in[2];
  const float* Wq = (const float*)d_in[3];
  const float* bq = (const float*)d_in[4];
  const float* Wk = (const float*)d_in[5];
  const float* bk = (const float*)d_in[6];
  const int* iter = (const int*)d_in[7];

  float* out = (float*)d_out;
  const size_t nH = (size_t)2 * NUM * NUM;
  float* Hout  = out;                 // (2,2048,2048)
  float* Wout  = out + nH;            // (2,2048,2048) — holds score temporarily
  float* DeOut = out + 2 * nH;        // (2,2048,1)
  float* DvOut = DeOut + 2 * NUM;     // (2,2048,1)
  float* WeOut = DvOut + 2 * NUM;     // (2,2048,1)

  float* colH = (float*)d_ws;         // 4096 floats
  float* colW = colH + 2 * NUM;       // 4096 floats

  // QT/KT (16 MB) live in the H region until topk_apply overwrites it
  float* QT = Hout;
  float* KT = Hout + (size_t)2 * NUM * CDIM;

  hipMemsetAsync(d_ws, 0, (size_t)2 * 2 * NUM * sizeof(float), stream);

  proj_kernel<<<dim3(NUM/64, CDIM/64, 4), 256, 0, stream>>>(Wq, bq, Wk, bk, vf, ef, QT, KT);
  score_kernel<<<dim3(NUM/128, NUM/128, 2), 256, 0, stream>>>(QT, KT, H0, Wout);
  topk_apply_kernel<<<dim3(2 * NUM), 256, 0, stream>>>(Wout, Hout, iter, DvOut, colH, colW);
  finalize_kernel<<<dim3(2), 1024, 0, stream>>>(colH, colW, DeOut, WeOut);
}

// Round 6
// 230.679 us; speedup vs baseline: 1.3738x; 1.3738x over previous
//
#include <hip/hip_runtime.h>
#include <math.h>

#define NUM 2048
#define CDIM 256
#define NUM_LAYER 4

// ---------------- projection: out[b][n][oc] = sum_c W[oc][c] x[b][c][n] + bias[oc]
__global__ __launch_bounds__(256) void proj_kernel(
    const float* __restrict__ Wq, const float* __restrict__ bq,
    const float* __restrict__ Wk, const float* __restrict__ bk,
    const float* __restrict__ vf, const float* __restrict__ ef,
    float* __restrict__ QT, float* __restrict__ KT)
{
  const int z = blockIdx.z;
  const int b = z >> 1, m = z & 1;
  const float* __restrict__ Wmat = m ? Wk : Wq;
  const float* __restrict__ bias = m ? bk : bq;
  const float* __restrict__ x = (m ? ef : vf) + (size_t)b * CDIM * NUM;
  float* __restrict__ out = (m ? KT : QT) + (size_t)b * NUM * CDIM;

  const int n0 = blockIdx.x * 64;
  const int o0 = blockIdx.y * 64;
  __shared__ float Xs[32][65];
  __shared__ float Ws[64][33];
  const int t = threadIdx.x;
  const int tx = t & 15, ty = t >> 4;

  float acc[4][4];
  #pragma unroll
  for (int a = 0; a < 4; a++)
    #pragma unroll
    for (int c = 0; c < 4; c++) acc[a][c] = 0.0f;

  for (int cc = 0; cc < CDIM; cc += 32) {
    #pragma unroll
    for (int e = 0; e < 2; e++) {
      int f = t * 2 + e;
      int row = f >> 4, c4 = f & 15;
      const float4 v = *(const float4*)(&x[(size_t)(cc + row) * NUM + n0 + c4 * 4]);
      Xs[row][c4*4+0] = v.x; Xs[row][c4*4+1] = v.y;
      Xs[row][c4*4+2] = v.z; Xs[row][c4*4+3] = v.w;
    }
    #pragma unroll
    for (int e = 0; e < 2; e++) {
      int f = t * 2 + e;
      int row = f >> 3, c4 = f & 7;
      const float4 v = *(const float4*)(&Wmat[(size_t)(o0 + row) * CDIM + cc + c4 * 4]);
      Ws[row][c4*4+0] = v.x; Ws[row][c4*4+1] = v.y;
      Ws[row][c4*4+2] = v.z; Ws[row][c4*4+3] = v.w;
    }
    __syncthreads();
    #pragma unroll
    for (int kk = 0; kk < 32; kk++) {
      float xv[4], wv[4];
      #pragma unroll
      for (int j = 0; j < 4; j++) xv[j] = Xs[kk][tx*4+j];
      #pragma unroll
      for (int j = 0; j < 4; j++) wv[j] = Ws[ty*4+j][kk];
      #pragma unroll
      for (int oi = 0; oi < 4; oi++)
        #pragma unroll
        for (int ni = 0; ni < 4; ni++)
          acc[oi][ni] = fmaf(wv[oi], xv[ni], acc[oi][ni]);
    }
    __syncthreads();
  }
  float bb[4];
  #pragma unroll
  for (int oi = 0; oi < 4; oi++) bb[oi] = bias[o0 + ty*4 + oi];
  #pragma unroll
  for (int ni = 0; ni < 4; ni++) {
    float4 v;
    v.x = acc[0][ni] + bb[0];
    v.y = acc[1][ni] + bb[1];
    v.z = acc[2][ni] + bb[2];
    v.w = acc[3][ni] + bb[3];
    *(float4*)(&out[(size_t)(n0 + tx*4 + ni) * CDIM + o0 + ty*4]) = v;
  }
}

// ---------------- score[b][o][i] = H0 * (1/8) * sum_h sigmoid(dot_h / sqrt(32))
// 128x128 tile, 256 threads, 8(o) x 8(i) per thread. LDS layout [k][n] with
// XOR swizzle on the COLUMN OFFSET (col ^ (k&28)), applied before adding the
// k*132 row base. No min-waves hint: let the allocator use up to 256 VGPRs so
// acc[64]+ssum[64] stay in registers (a (256,3) cap risks scratch spills).
__global__ __launch_bounds__(256) void score_kernel(
    const float* __restrict__ QT, const float* __restrict__ KT,
    const float* __restrict__ H0, float* __restrict__ score)
{
  const int b = blockIdx.z;
  const int i0 = blockIdx.x * 128;
  const int o0 = blockIdx.y * 128;
  const float* __restrict__ Qb = QT + (size_t)b * NUM * CDIM;
  const float* __restrict__ Kb = KT + (size_t)b * NUM * CDIM;
  __shared__ float qs[32 * 132];
  __shared__ float ks[32 * 132];
  const int t = threadIdx.x;
  const int lane = t & 63, wave = t >> 6;
  const int ifr = lane & 7, ofr = lane >> 3;
  const int i_off = (wave & 1) * 64 + ifr * 8;
  const int o_off = (wave >> 1) * 64 + ofr * 8;

  float ssum[8][8];
  #pragma unroll
  for (int a = 0; a < 8; a++)
    #pragma unroll
    for (int c = 0; c < 8; c++) ssum[a][c] = 0.0f;

  const float SC = -1.4426950408889634f * 0.17677669529663687f;  // -log2(e)/sqrt(32)
  const int row_s = t >> 3, c4 = t & 7;
  const int swz_st = c4 << 2;              // == k&28 for k = c4*4+qq, qq<4

  for (int h = 0; h < 8; h++) {
    #pragma unroll
    for (int e = 0; e < 4; e++) {
      const int row = row_s + 32 * e;
      const int rc = row ^ swz_st;
      const float4 q = *(const float4*)(&Qb[(size_t)(o0 + row) * CDIM + h*32 + c4*4]);
      qs[(c4*4+0)*132 + rc] = q.x; qs[(c4*4+1)*132 + rc] = q.y;
      qs[(c4*4+2)*132 + rc] = q.z; qs[(c4*4+3)*132 + rc] = q.w;
      const float4 kv = *(const float4*)(&Kb[(size_t)(i0 + row) * CDIM + h*32 + c4*4]);
      ks[(c4*4+0)*132 + rc] = kv.x; ks[(c4*4+1)*132 + rc] = kv.y;
      ks[(c4*4+2)*132 + rc] = kv.z; ks[(c4*4+3)*132 + rc] = kv.w;
    }
    __syncthreads();
    float acc[8][8];
    #pragma unroll
    for (int a = 0; a < 8; a++)
      #pragma unroll
      for (int c = 0; c < 8; c++) acc[a][c] = 0.0f;
    #pragma unroll 4
    for (int kk = 0; kk < 32; kk++) {
      const int g = kk & 28;
      const int rowbase = kk * 132;
      const int oq = o_off ^ g;
      const int iq = i_off ^ g;
      const float4 qa  = *(const float4*)(&qs[rowbase + oq]);
      const float4 qbv = *(const float4*)(&qs[rowbase + (oq ^ 4)]);
      const float4 ka  = *(const float4*)(&ks[rowbase + iq]);
      const float4 kbv = *(const float4*)(&ks[rowbase + (iq ^ 4)]);
      const float qv[8] = {qa.x, qa.y, qa.z, qa.w, qbv.x, qbv.y, qbv.z, qbv.w};
      const float kv[8] = {ka.x, ka.y, ka.z, ka.w, kbv.x, kbv.y, kbv.z, kbv.w};
      #pragma unroll
      for (int oj = 0; oj < 8; oj++)
        #pragma unroll
        for (int ij = 0; ij < 8; ij++)
          acc[oj][ij] = fmaf(qv[oj], kv[ij], acc[oj][ij]);
    }
    __syncthreads();
    #pragma unroll
    for (int oj = 0; oj < 8; oj++)
      #pragma unroll
      for (int ij = 0; ij < 8; ij++) {
        float z = __builtin_amdgcn_exp2f(acc[oj][ij] * SC);
        ssum[oj][ij] += __builtin_amdgcn_rcpf(1.0f + z);
      }
  }
  #pragma unroll
  for (int oj = 0; oj < 8; oj++) {
    const int o = o0 + o_off + oj;
    const size_t base = ((size_t)b * NUM + o) * NUM + i0 + i_off;
    const float4 h0a = *(const float4*)(&H0[base]);
    const float4 h0b = *(const float4*)(&H0[base + 4]);
    float4 sa, sb;
    sa.x = h0a.x * ssum[oj][0] * 0.125f;
    sa.y = h0a.y * ssum[oj][1] * 0.125f;
    sa.z = h0a.z * ssum[oj][2] * 0.125f;
    sa.w = h0a.w * ssum[oj][3] * 0.125f;
    sb.x = h0b.x * ssum[oj][4] * 0.125f;
    sb.y = h0b.y * ssum[oj][5] * 0.125f;
    sb.z = h0b.z * ssum[oj][6] * 0.125f;
    sb.w = h0b.w * ssum[oj][7] * 0.125f;
    *(float4*)(&score[base]) = sa;
    *(float4*)(&score[base + 4]) = sb;
  }
}

// ---------------- fused: exact k-th largest (radix select on float bits, all >= 0)
// + W/H write + row count -> Dv. NO global col atomics (memory-side atomic
// serialization on 16 KB cost ~40 µs + 53 MB extra write traffic in R5).
__global__ __launch_bounds__(256) void topk_apply_kernel(
    float* __restrict__ scoreW, float* __restrict__ Hout,
    const int* __restrict__ iterp, float* __restrict__ DvOut)
{
  const int row = blockIdx.x;
  __shared__ unsigned int hist[4][256];
  __shared__ unsigned int cum[257];
  __shared__ unsigned int s_sel, s_rem;
  __shared__ float red[4];
  const int t = threadIdx.x;
  const int wid = t >> 6, lane = t & 63;
  unsigned int* __restrict__ srow = (unsigned int*)scoreW + (size_t)row * NUM;

  unsigned int v[8];
  #pragma unroll
  for (int j = 0; j < 8; j++) v[j] = srow[t + 256*j];

  const int it = iterp[0];
  int k = (int)((double)NUM * 0.1 * (double)(NUM_LAYER - 1 - it) + 0.5);
  if (k < 1) k = 1;
  if (k > NUM) k = NUM;

  unsigned int prefix = 0;
  unsigned int rem = (unsigned int)k;
  unsigned int* hflat = &hist[0][0];

  for (int pass = 3; pass >= 0; pass--) {
    const int shift = pass * 8;
    const unsigned int pmask = (pass == 3) ? 0u : (0xFFFFFFFFu << (shift + 8));
    #pragma unroll
    for (int j = 0; j < 4; j++) hflat[t + 256*j] = 0;
    __syncthreads();
    unsigned int zc = 0;
    #pragma unroll
    for (int j = 0; j < 8; j++) {
      unsigned int val = v[j];
      if ((val & pmask) == prefix) {
        unsigned int bin = (val >> shift) & 255u;
        if (bin) atomicAdd(&hist[wid][bin], 1u);
        else zc++;
      }
    }
    #pragma unroll
    for (int off = 32; off > 0; off >>= 1) zc += __shfl_down(zc, off, 64);
    if (lane == 0 && zc) atomicAdd(&hist[wid][0], zc);
    __syncthreads();
    if (t < 64) {
      unsigned int T[4], s[4];
      #pragma unroll
      for (int q = 0; q < 4; q++)
        T[q] = hist[0][t*4+q] + hist[1][t*4+q] + hist[2][t*4+q] + hist[3][t*4+q];
      s[3] = T[3];
      s[2] = T[2] + s[3];
      s[1] = T[1] + s[2];
      s[0] = T[0] + s[1];
      unsigned int tot = s[0];
      #pragma unroll
      for (int off = 1; off < 64; off <<= 1) {
        unsigned int y = __shfl_down(tot, off, 64);
        if (lane + off < 64) tot += y;
      }
      const unsigned int above_chunk = tot - s[0];
      #pragma unroll
      for (int q = 0; q < 4; q++) cum[t*4+q] = s[q] + above_chunk;
      if (t == 0) cum[256] = 0;
    }
    __syncthreads();
    unsigned int c = cum[t], above = cum[t + 1];
    if (c >= rem && above < rem) { s_sel = (unsigned int)t; s_rem = rem - above; }
    __syncthreads();
    prefix |= (s_sel << shift);
    rem = s_rem;
    __syncthreads();
  }

  const unsigned int amin = prefix;
  float* __restrict__ Hrow = Hout + (size_t)row * NUM;
  float cnt = 0.0f;
  #pragma unroll
  for (int j = 0; j < 8; j++) {
    const int i = t + 256*j;
    unsigned int val = v[j];
    unsigned int w = (val >= amin) ? val : 0u;
    float hh = (w != 0u) ? 1.0f : 0.0f;
    srow[i] = w;
    Hrow[i] = hh;
    cnt += hh;
  }
  #pragma unroll
  for (int off = 32; off > 0; off >>= 1) cnt += __shfl_down(cnt, off, 64);
  if (lane == 0) red[wid] = cnt;
  __syncthreads();
  if (t == 0) {
    float tot = red[0] + red[1] + red[2] + red[3];
    DvOut[row] = 1.0f / (tot + 1e-10f);
  }
}

// ---------------- column partial sums over o; colH derived from W>0.
// 65K atomics total (one per thread after 128-row partial sum) - no contention.
__global__ __launch_bounds__(256) void colsum_kernel(
    const float* __restrict__ Wmat,
    float* __restrict__ colH, float* __restrict__ colW)
{
  const int b = blockIdx.z;
  const int i = blockIdx.x * 256 + threadIdx.x;
  const int o0 = blockIdx.y * 128;
  float sh = 0.0f, sw = 0.0f;
  for (int o = 0; o < 128; o++) {
    size_t idx = ((size_t)b * NUM + o0 + o) * NUM + i;
    float w = Wmat[idx];
    sw += w;
    sh += (w > 0.0f) ? 1.0f : 0.0f;
  }
  atomicAdd(&colH[b * NUM + i], sh);
  atomicAdd(&colW[b * NUM + i], sw);
}

// ---------------- De = 1/(colH+eps); W_edge = colW / max(||colW||_2, 1e-12)
__global__ __launch_bounds__(1024) void finalize_kernel(
    const float* __restrict__ colH, const float* __restrict__ colW,
    float* __restrict__ De, float* __restrict__ We)
{
  const int b = blockIdx.x;
  const int t = threadIdx.x;
  float cw[2];
  float sq = 0.0f;
  #pragma unroll
  for (int j = 0; j < 2; j++) {
    int i = t + 1024*j;
    float ch = colH[b * NUM + i];
    De[b * NUM + i] = 1.0f / (ch + 1e-10f);
    cw[j] = colW[b * NUM + i];
    sq += cw[j] * cw[j];
  }
  for (int off = 32; off > 0; off >>= 1) sq += __shfl_down(sq, off, 64);
  __shared__ float red[16];
  __shared__ float s_nrm;
  if ((t & 63) == 0) red[t >> 6] = sq;
  __syncthreads();
  if (t == 0) {
    float tot = 0.0f;
    for (int i2 = 0; i2 < 16; i2++) tot += red[i2];
    s_nrm = fmaxf(sqrtf(tot), 1e-12f);
  }
  __syncthreads();
  #pragma unroll
  for (int j = 0; j < 2; j++)
    We[b * NUM + t + 1024*j] = cw[j] / s_nrm;
}

extern "C" void kernel_launch(void* const* d_in, const int* in_sizes, int n_in,
                              void* d_out, int out_size, void* d_ws, size_t ws_size,
                              hipStream_t stream) {
  const float* H0 = (const float*)d_in[0];
  const float* vf = (const float*)d_in[1];
  const float* ef = (const float*)d_in[2];
  const float* Wq = (const float*)d_in[3];
  const float* bq = (const float*)d_in[4];
  const float* Wk = (const float*)d_in[5];
  const float* bk = (const float*)d_in[6];
  const int* iter = (const int*)d_in[7];

  float* out = (float*)d_out;
  const size_t nH = (size_t)2 * NUM * NUM;
  float* Hout  = out;                 // (2,2048,2048)
  float* Wout  = out + nH;            // (2,2048,2048) — holds score temporarily
  float* DeOut = out + 2 * nH;        // (2,2048,1)
  float* DvOut = DeOut + 2 * NUM;     // (2,2048,1)
  float* WeOut = DvOut + 2 * NUM;     // (2,2048,1)

  float* colH = (float*)d_ws;         // 4096 floats
  float* colW = colH + 2 * NUM;       // 4096 floats

  // QT/KT (16 MB) live in the H region until topk_apply overwrites it
  float* QT = Hout;
  float* KT = Hout + (size_t)2 * NUM * CDIM;

  hipMemsetAsync(d_ws, 0, (size_t)2 * 2 * NUM * sizeof(float), stream);

  proj_kernel<<<dim3(NUM/64, CDIM/64, 4), 256, 0, stream>>>(Wq, bq, Wk, bk, vf, ef, QT, KT);
  score_kernel<<<dim3(NUM/128, NUM/128, 2), 256, 0, stream>>>(QT, KT, H0, Wout);
  topk_apply_kernel<<<dim3(2 * NUM), 256, 0, stream>>>(Wout, Hout, iter, DvOut);
  colsum_kernel<<<dim3(NUM/256, NUM/128, 2), 256, 0, stream>>>(Wout, colH, colW);
  finalize_kernel<<<dim3(2), 1024, 0, stream>>>(colH, colW, DeOut, WeOut);
}

// Round 7
// 224.778 us; speedup vs baseline: 1.4098x; 1.0263x over previous
//
#include <hip/hip_runtime.h>
#include <math.h>

#define NUM 2048
#define CDIM 256
#define NUM_LAYER 4

typedef float v2f __attribute__((ext_vector_type(2)));

// ---------------- projection: out[b][n][oc] = sum_c W[oc][c] x[b][c][n] + bias[oc]
__global__ __launch_bounds__(256) void proj_kernel(
    const float* __restrict__ Wq, const float* __restrict__ bq,
    const float* __restrict__ Wk, const float* __restrict__ bk,
    const float* __restrict__ vf, const float* __restrict__ ef,
    float* __restrict__ QT, float* __restrict__ KT)
{
  const int z = blockIdx.z;
  const int b = z >> 1, m = z & 1;
  const float* __restrict__ Wmat = m ? Wk : Wq;
  const float* __restrict__ bias = m ? bk : bq;
  const float* __restrict__ x = (m ? ef : vf) + (size_t)b * CDIM * NUM;
  float* __restrict__ out = (m ? KT : QT) + (size_t)b * NUM * CDIM;

  const int n0 = blockIdx.x * 64;
  const int o0 = blockIdx.y * 64;
  __shared__ float Xs[32][65];
  __shared__ float Ws[64][33];
  const int t = threadIdx.x;
  const int tx = t & 15, ty = t >> 4;

  float acc[4][4];
  #pragma unroll
  for (int a = 0; a < 4; a++)
    #pragma unroll
    for (int c = 0; c < 4; c++) acc[a][c] = 0.0f;

  for (int cc = 0; cc < CDIM; cc += 32) {
    #pragma unroll
    for (int e = 0; e < 2; e++) {
      int f = t * 2 + e;
      int row = f >> 4, c4 = f & 15;
      const float4 v = *(const float4*)(&x[(size_t)(cc + row) * NUM + n0 + c4 * 4]);
      Xs[row][c4*4+0] = v.x; Xs[row][c4*4+1] = v.y;
      Xs[row][c4*4+2] = v.z; Xs[row][c4*4+3] = v.w;
    }
    #pragma unroll
    for (int e = 0; e < 2; e++) {
      int f = t * 2 + e;
      int row = f >> 3, c4 = f & 7;
      const float4 v = *(const float4*)(&Wmat[(size_t)(o0 + row) * CDIM + cc + c4 * 4]);
      Ws[row][c4*4+0] = v.x; Ws[row][c4*4+1] = v.y;
      Ws[row][c4*4+2] = v.z; Ws[row][c4*4+3] = v.w;
    }
    __syncthreads();
    #pragma unroll
    for (int kk = 0; kk < 32; kk++) {
      float xv[4], wv[4];
      #pragma unroll
      for (int j = 0; j < 4; j++) xv[j] = Xs[kk][tx*4+j];
      #pragma unroll
      for (int j = 0; j < 4; j++) wv[j] = Ws[ty*4+j][kk];
      #pragma unroll
      for (int oi = 0; oi < 4; oi++)
        #pragma unroll
        for (int ni = 0; ni < 4; ni++)
          acc[oi][ni] = fmaf(wv[oi], xv[ni], acc[oi][ni]);
    }
    __syncthreads();
  }
  float bb[4];
  #pragma unroll
  for (int oi = 0; oi < 4; oi++) bb[oi] = bias[o0 + ty*4 + oi];
  #pragma unroll
  for (int ni = 0; ni < 4; ni++) {
    float4 v;
    v.x = acc[0][ni] + bb[0];
    v.y = acc[1][ni] + bb[1];
    v.z = acc[2][ni] + bb[2];
    v.w = acc[3][ni] + bb[3];
    *(float4*)(&out[(size_t)(n0 + tx*4 + ni) * CDIM + o0 + ty*4]) = v;
  }
}

// ---------------- score[b][o][i] = H0 * (1/8) * sum_h sigmoid(dot_h / sqrt(32))
// 128x128 tile, 256 threads, 8x8/thread. XOR-swizzled LDS (verified R6,
// conflicts=0). NEW: double-buffered staging (1 barrier/head, global loads
// for h+1 issued before compute of h) + v2f packed FMA (v_pk_fma_f32).
// Per-element FMA order identical to R6 -> bit-identical scores.
__global__ __launch_bounds__(256) void score_kernel(
    const float* __restrict__ QT, const float* __restrict__ KT,
    const float* __restrict__ H0, float* __restrict__ score)
{
  const int b = blockIdx.z;
  const int i0 = blockIdx.x * 128;
  const int o0 = blockIdx.y * 128;
  const float* __restrict__ Qb = QT + (size_t)b * NUM * CDIM;
  const float* __restrict__ Kb = KT + (size_t)b * NUM * CDIM;
  __shared__ float qs[2][32 * 132];
  __shared__ float ks[2][32 * 132];
  const int t = threadIdx.x;
  const int lane = t & 63, wave = t >> 6;
  const int ifr = lane & 7, ofr = lane >> 3;
  const int i_off = (wave & 1) * 64 + ifr * 8;
  const int o_off = (wave >> 1) * 64 + ofr * 8;

  v2f ssum[8][4];
  #pragma unroll
  for (int a = 0; a < 8; a++)
    #pragma unroll
    for (int c = 0; c < 4; c++) ssum[a][c] = (v2f){0.0f, 0.0f};

  const float SC = -1.4426950408889634f * 0.17677669529663687f;  // -log2(e)/sqrt(32)
  const int row_s = t >> 3, c4 = t & 7;
  const int swz_st = c4 << 2;              // == k&28 for k = c4*4+qq, qq<4

  float4 rq[4], rk[4];
  // prologue: load + stage head 0 into buffer 0
  #pragma unroll
  for (int e = 0; e < 4; e++) {
    const int row = row_s + 32 * e;
    rq[e] = *(const float4*)(&Qb[(size_t)(o0 + row) * CDIM + c4 * 4]);
    rk[e] = *(const float4*)(&Kb[(size_t)(i0 + row) * CDIM + c4 * 4]);
  }
  #pragma unroll
  for (int e = 0; e < 4; e++) {
    const int rc = (row_s + 32 * e) ^ swz_st;
    qs[0][(c4*4+0)*132 + rc] = rq[e].x; qs[0][(c4*4+1)*132 + rc] = rq[e].y;
    qs[0][(c4*4+2)*132 + rc] = rq[e].z; qs[0][(c4*4+3)*132 + rc] = rq[e].w;
    ks[0][(c4*4+0)*132 + rc] = rk[e].x; ks[0][(c4*4+1)*132 + rc] = rk[e].y;
    ks[0][(c4*4+2)*132 + rc] = rk[e].z; ks[0][(c4*4+3)*132 + rc] = rk[e].w;
  }
  __syncthreads();

  for (int h = 0; h < 8; h++) {
    const int buf = h & 1;
    if (h < 7) {
      #pragma unroll
      for (int e = 0; e < 4; e++) {
        const int row = row_s + 32 * e;
        rq[e] = *(const float4*)(&Qb[(size_t)(o0 + row) * CDIM + (h+1)*32 + c4*4]);
        rk[e] = *(const float4*)(&Kb[(size_t)(i0 + row) * CDIM + (h+1)*32 + c4*4]);
      }
    }
    const float* __restrict__ q_ = qs[buf];
    const float* __restrict__ k_ = ks[buf];
    v2f acc[8][4];
    #pragma unroll
    for (int a = 0; a < 8; a++)
      #pragma unroll
      for (int c = 0; c < 4; c++) acc[a][c] = (v2f){0.0f, 0.0f};
    #pragma unroll 4
    for (int kk = 0; kk < 32; kk++) {
      const int g = kk & 28;
      const int rowbase = kk * 132;
      const int oq = o_off ^ g;
      const int iq = i_off ^ g;
      const float4 qa  = *(const float4*)(&q_[rowbase + oq]);
      const float4 qbv = *(const float4*)(&q_[rowbase + (oq ^ 4)]);
      const float4 ka  = *(const float4*)(&k_[rowbase + iq]);
      const float4 kbv = *(const float4*)(&k_[rowbase + (iq ^ 4)]);
      const float qv[8] = {qa.x, qa.y, qa.z, qa.w, qbv.x, qbv.y, qbv.z, qbv.w};
      const v2f kv2[4] = {{ka.x, ka.y}, {ka.z, ka.w}, {kbv.x, kbv.y}, {kbv.z, kbv.w}};
      #pragma unroll
      for (int oj = 0; oj < 8; oj++) {
        const v2f qq = {qv[oj], qv[oj]};
        #pragma unroll
        for (int p = 0; p < 4; p++)
          acc[oj][p] = __builtin_elementwise_fma(qq, kv2[p], acc[oj][p]);
      }
    }
    #pragma unroll
    for (int oj = 0; oj < 8; oj++)
      #pragma unroll
      for (int p = 0; p < 4; p++) {
        const v2f a = acc[oj][p];
        v2f r;
        r.x = __builtin_amdgcn_rcpf(1.0f + __builtin_amdgcn_exp2f(a.x * SC));
        r.y = __builtin_amdgcn_rcpf(1.0f + __builtin_amdgcn_exp2f(a.y * SC));
        ssum[oj][p] += r;
      }
    if (h < 7) {
      const int nb = buf ^ 1;
      #pragma unroll
      for (int e = 0; e < 4; e++) {
        const int rc = (row_s + 32 * e) ^ swz_st;
        qs[nb][(c4*4+0)*132 + rc] = rq[e].x; qs[nb][(c4*4+1)*132 + rc] = rq[e].y;
        qs[nb][(c4*4+2)*132 + rc] = rq[e].z; qs[nb][(c4*4+3)*132 + rc] = rq[e].w;
        ks[nb][(c4*4+0)*132 + rc] = rk[e].x; ks[nb][(c4*4+1)*132 + rc] = rk[e].y;
        ks[nb][(c4*4+2)*132 + rc] = rk[e].z; ks[nb][(c4*4+3)*132 + rc] = rk[e].w;
      }
      __syncthreads();
    }
  }
  #pragma unroll
  for (int oj = 0; oj < 8; oj++) {
    const int o = o0 + o_off + oj;
    const size_t base = ((size_t)b * NUM + o) * NUM + i0 + i_off;
    const float* ss = (const float*)&ssum[oj][0];
    const float4 h0a = *(const float4*)(&H0[base]);
    const float4 h0b = *(const float4*)(&H0[base + 4]);
    float4 sa, sb;
    sa.x = h0a.x * ss[0] * 0.125f;
    sa.y = h0a.y * ss[1] * 0.125f;
    sa.z = h0a.z * ss[2] * 0.125f;
    sa.w = h0a.w * ss[3] * 0.125f;
    sb.x = h0b.x * ss[4] * 0.125f;
    sb.y = h0b.y * ss[5] * 0.125f;
    sb.z = h0b.z * ss[6] * 0.125f;
    sb.w = h0b.w * ss[7] * 0.125f;
    *(float4*)(&score[base]) = sa;
    *(float4*)(&score[base + 4]) = sb;
  }
}

// ---------------- fused: exact k-th largest (radix select on float bits, all >= 0)
// + W/H write + row count -> Dv. Vectorized uint4/float4 global access.
__global__ __launch_bounds__(256) void topk_apply_kernel(
    float* __restrict__ scoreW, float* __restrict__ Hout,
    const int* __restrict__ iterp, float* __restrict__ DvOut)
{
  const int row = blockIdx.x;
  __shared__ unsigned int hist[4][256];
  __shared__ unsigned int cum[257];
  __shared__ unsigned int s_sel, s_rem;
  __shared__ float red[4];
  const int t = threadIdx.x;
  const int wid = t >> 6, lane = t & 63;
  unsigned int* __restrict__ srow = (unsigned int*)scoreW + (size_t)row * NUM;

  const uint4 va = ((const uint4*)srow)[t*2];
  const uint4 vb = ((const uint4*)srow)[t*2+1];
  unsigned int v[8] = {va.x, va.y, va.z, va.w, vb.x, vb.y, vb.z, vb.w};

  const int it = iterp[0];
  int k = (int)((double)NUM * 0.1 * (double)(NUM_LAYER - 1 - it) + 0.5);
  if (k < 1) k = 1;
  if (k > NUM) k = NUM;

  unsigned int prefix = 0;
  unsigned int rem = (unsigned int)k;
  unsigned int* hflat = &hist[0][0];

  for (int pass = 3; pass >= 0; pass--) {
    const int shift = pass * 8;
    const unsigned int pmask = (pass == 3) ? 0u : (0xFFFFFFFFu << (shift + 8));
    #pragma unroll
    for (int j = 0; j < 4; j++) hflat[t + 256*j] = 0;
    __syncthreads();
    unsigned int zc = 0;
    #pragma unroll
    for (int j = 0; j < 8; j++) {
      unsigned int val = v[j];
      if ((val & pmask) == prefix) {
        unsigned int bin = (val >> shift) & 255u;
        if (bin) atomicAdd(&hist[wid][bin], 1u);
        else zc++;
      }
    }
    #pragma unroll
    for (int off = 32; off > 0; off >>= 1) zc += __shfl_down(zc, off, 64);
    if (lane == 0 && zc) atomicAdd(&hist[wid][0], zc);
    __syncthreads();
    if (t < 64) {
      unsigned int T[4], s[4];
      #pragma unroll
      for (int q = 0; q < 4; q++)
        T[q] = hist[0][t*4+q] + hist[1][t*4+q] + hist[2][t*4+q] + hist[3][t*4+q];
      s[3] = T[3];
      s[2] = T[2] + s[3];
      s[1] = T[1] + s[2];
      s[0] = T[0] + s[1];
      unsigned int tot = s[0];
      #pragma unroll
      for (int off = 1; off < 64; off <<= 1) {
        unsigned int y = __shfl_down(tot, off, 64);
        if (lane + off < 64) tot += y;
      }
      const unsigned int above_chunk = tot - s[0];
      #pragma unroll
      for (int q = 0; q < 4; q++) cum[t*4+q] = s[q] + above_chunk;
      if (t == 0) cum[256] = 0;
    }
    __syncthreads();
    unsigned int c = cum[t], above = cum[t + 1];
    if (c >= rem && above < rem) { s_sel = (unsigned int)t; s_rem = rem - above; }
    __syncthreads();
    prefix |= (s_sel << shift);
    rem = s_rem;
    __syncthreads();
  }

  const unsigned int amin = prefix;
  float* __restrict__ Hrow = Hout + (size_t)row * NUM;
  unsigned int w[8];
  float hh[8];
  float cnt = 0.0f;
  #pragma unroll
  for (int j = 0; j < 8; j++) {
    w[j] = (v[j] >= amin) ? v[j] : 0u;
    hh[j] = (w[j] != 0u) ? 1.0f : 0.0f;
    cnt += hh[j];
  }
  ((uint4*)srow)[t*2]   = make_uint4(w[0], w[1], w[2], w[3]);
  ((uint4*)srow)[t*2+1] = make_uint4(w[4], w[5], w[6], w[7]);
  ((float4*)Hrow)[t*2]   = make_float4(hh[0], hh[1], hh[2], hh[3]);
  ((float4*)Hrow)[t*2+1] = make_float4(hh[4], hh[5], hh[6], hh[7]);
  #pragma unroll
  for (int off = 32; off > 0; off >>= 1) cnt += __shfl_down(cnt, off, 64);
  if (lane == 0) red[wid] = cnt;
  __syncthreads();
  if (t == 0) {
    float tot = red[0] + red[1] + red[2] + red[3];
    DvOut[row] = 1.0f / (tot + 1e-10f);
  }
}

// ---------------- column partial sums over o; colH derived from W>0.
__global__ __launch_bounds__(256) void colsum_kernel(
    const float* __restrict__ Wmat,
    float* __restrict__ colH, float* __restrict__ colW)
{
  const int b = blockIdx.z;
  const int i = blockIdx.x * 256 + threadIdx.x;
  const int o0 = blockIdx.y * 128;
  float sh = 0.0f, sw = 0.0f;
  for (int o = 0; o < 128; o++) {
    size_t idx = ((size_t)b * NUM + o0 + o) * NUM + i;
    float w = Wmat[idx];
    sw += w;
    sh += (w > 0.0f) ? 1.0f : 0.0f;
  }
  atomicAdd(&colH[b * NUM + i], sh);
  atomicAdd(&colW[b * NUM + i], sw);
}

// ---------------- De = 1/(colH+eps); W_edge = colW / max(||colW||_2, 1e-12)
__global__ __launch_bounds__(1024) void finalize_kernel(
    const float* __restrict__ colH, const float* __restrict__ colW,
    float* __restrict__ De, float* __restrict__ We)
{
  const int b = blockIdx.x;
  const int t = threadIdx.x;
  float cw[2];
  float sq = 0.0f;
  #pragma unroll
  for (int j = 0; j < 2; j++) {
    int i = t + 1024*j;
    float ch = colH[b * NUM + i];
    De[b * NUM + i] = 1.0f / (ch + 1e-10f);
    cw[j] = colW[b * NUM + i];
    sq += cw[j] * cw[j];
  }
  for (int off = 32; off > 0; off >>= 1) sq += __shfl_down(sq, off, 64);
  __shared__ float red[16];
  __shared__ float s_nrm;
  if ((t & 63) == 0) red[t >> 6] = sq;
  __syncthreads();
  if (t == 0) {
    float tot = 0.0f;
    for (int i2 = 0; i2 < 16; i2++) tot += red[i2];
    s_nrm = fmaxf(sqrtf(tot), 1e-12f);
  }
  __syncthreads();
  #pragma unroll
  for (int j = 0; j < 2; j++)
    We[b * NUM + t + 1024*j] = cw[j] / s_nrm;
}

extern "C" void kernel_launch(void* const* d_in, const int* in_sizes, int n_in,
                              void* d_out, int out_size, void* d_ws, size_t ws_size,
                              hipStream_t stream) {
  const float* H0 = (const float*)d_in[0];
  const float* vf = (const float*)d_in[1];
  const float* ef = (const float*)d_in[2];
  const float* Wq = (const float*)d_in[3];
  const float* bq = (const float*)d_in[4];
  const float* Wk = (const float*)d_in[5];
  const float* bk = (const float*)d_in[6];
  const int* iter = (const int*)d_in[7];

  float* out = (float*)d_out;
  const size_t nH = (size_t)2 * NUM * NUM;
  float* Hout  = out;                 // (2,2048,2048)
  float* Wout  = out + nH;            // (2,2048,2048) — holds score temporarily
  float* DeOut = out + 2 * nH;        // (2,2048,1)
  float* DvOut = DeOut + 2 * NUM;     // (2,2048,1)
  float* WeOut = DvOut + 2 * NUM;     // (2,2048,1)

  float* colH = (float*)d_ws;         // 4096 floats
  float* colW = colH + 2 * NUM;       // 4096 floats

  // QT/KT (16 MB) live in the H region until topk_apply overwrites it
  float* QT = Hout;
  float* KT = Hout + (size_t)2 * NUM * CDIM;

  hipMemsetAsync(d_ws, 0, (size_t)2 * 2 * NUM * sizeof(float), stream);

  proj_kernel<<<dim3(NUM/64, CDIM/64, 4), 256, 0, stream>>>(Wq, bq, Wk, bk, vf, ef, QT, KT);
  score_kernel<<<dim3(NUM/128, NUM/128, 2), 256, 0, stream>>>(QT, KT, H0, Wout);
  topk_apply_kernel<<<dim3(2 * NUM), 256, 0, stream>>>(Wout, Hout, iter, DvOut);
  colsum_kernel<<<dim3(NUM/256, NUM/128, 2), 256, 0, stream>>>(Wout, colH, colW);
  finalize_kernel<<<dim3(2), 1024, 0, stream>>>(colH, colW, DeOut, WeOut);
}